// Round 1
// baseline (1013.419 us; speedup 1.0000x reference)
//
#include <hip/hip_runtime.h>
#include <hip/hip_cooperative_groups.h>

namespace cg = cooperative_groups;

// RecursiveNN, perfect binary tree, 8192 leaves, EMBED=512.
// LEVEL-MAJOR H layout: level h stored as dense [M_h][512] at row offset
// roff(h) = 16384 - 2^(14-h). Children of (h,m) are (h-1,2m),(h-1,2m+1), so
// level h's GEMM input [M][1024] is EXACTLY the previous level's buffer.
// Numerics: fp16 hi+lo split H and W, 3-term MFMA (hh,hl,lh) => fp32-level.
//
// r-this: the 15 serialized launches cost ~140us of boundary/drain overhead
// (work-sum is only ~95us: ~1GB traffic @ 12.5TB/s + 15us MFMA). Fuse
// EVERYTHING into one cooperative kernel (512 blocks x 256 thr, 68KB LDS ->
// 2 blocks/CU co-resident guaranteed by hipLaunchCooperativeKernel) with
// grid.sync() between levels. Per-level math is byte-identical to the
// separate kernels (same device functions). Old per-level path retained as
// fallback if the cooperative launch is rejected.

#define EMBED 512
#define K2    1024
#define WOFF  (EMBED * K2)

typedef _Float16 half8 __attribute__((ext_vector_type(8)));
typedef float    floatx4 __attribute__((ext_vector_type(4)));

__device__ __forceinline__ float relu_f(float x) { return fmaxf(x, 0.0f); }

#define GLDS16(gp, lp)                                                        \
    __builtin_amdgcn_global_load_lds(                                         \
        (const __attribute__((address_space(1))) void*)(gp),                  \
        (__attribute__((address_space(3))) void*)(lp), 16, 0, 0)

#define MFMA16(a, b, c) __builtin_amdgcn_mfma_f32_16x16x32_f16(a, b, c, 0, 0, 0)

// ---------------------------------------------------------------------------
// pack W into fp16 hi/lo MFMA-B fragment order + leaves into level-0 rows.
// bx = block id in [0,256).
__device__ void dev_packleaf(const float* __restrict__ W,
                             const float* __restrict__ emb,
                             const int* __restrict__ word,
                             _Float16* __restrict__ Whp,
                             _Float16* __restrict__ Hh, _Float16* __restrict__ Hl,
                             int nLeaves, int bx)
{
    int tid = threadIdx.x;
    int wave = tid >> 6, lane = tid & 63;

    {   // ---- pack W: 65536 jobs = 256 blocks x 256 threads
        int t = bx * 256 + tid;
        int n = t >> 7, kc = t & 127;
        const float* src = W + (size_t)n * K2 + kc * 8;
        int s = kc >> 2, quad = kc & 3;
        int ln = (quad << 4) | (n & 15);
        size_t off = (size_t)(n >> 4) * 16384 + (size_t)s * 512 + (size_t)ln * 8;
        half8 hi, lo;
#pragma unroll
        for (int j = 0; j < 8; ++j) {
            float w = src[j];
            _Float16 h16 = (_Float16)w;
            hi[j] = h16;
            lo[j] = (_Float16)(w - (float)h16);
        }
        *(half8*)(Whp + off) = hi;
        *(half8*)(Whp + WOFF + off) = lo;
    }
    {   // ---- leaves -> level-0 rows (m-order, coalesced)
#pragma unroll
        for (int i = 0; i < 8; ++i) {
            int m = bx * 32 + wave * 8 + i;
            if (m < nLeaves) {
                int wd = word[2 * m - __popc(m)];    // post-order leaf id
                const float4* src = (const float4*)(emb + (size_t)wd * EMBED) + lane * 2;
                float4 a = src[0], b = src[1];
                float v[8] = {a.x, a.y, a.z, a.w, b.x, b.y, b.z, b.w};
                half8 hi, lo;
#pragma unroll
                for (int j = 0; j < 8; ++j) {
                    float x = relu_f(v[j]);
                    _Float16 h16 = (_Float16)x;
                    hi[j] = h16;
                    lo[j] = (_Float16)(x - (float)h16);
                }
                *(half8*)(Hh + (size_t)m * EMBED + lane * 8) = hi;
                *(half8*)(Hl + (size_t)m * EMBED + lane * 8) = lo;
            }
        }
    }
}

// ---------------------------------------------------------------------------
// Level GEMM for h=1,2 (M multiple of 64). Block = 64 rows x 64 cols,
// 4 waves: slice = wave>>1 (K-half = child), nh = wave&1 (col-half).
__device__ void dev_gemm_lvl(const _Float16* __restrict__ Ap,
                             const _Float16* __restrict__ Wp,
                             const float* __restrict__ bW,
                             _Float16* __restrict__ Cp, int hoff,
                             int bx, int by)
{
    __shared__ _Float16 As[16384];              // 32 KB: 32 fragment slots x 1 KB
    __shared__ float Red[4096];                 // 16 KB: 64x64 fp32

    int tid = threadIdx.x;
    int wave = tid >> 6, lane = tid & 63;
    int q = lane >> 4, r = lane & 15;
    int slice = wave >> 1, nh = wave & 1;
    int bm0 = bx * 64, bn0 = by * 64;

    const _Float16* Asrc = Ap + (size_t)(nh ? hoff : 0)
                         + (size_t)(bm0 + r) * 1024 + slice * 512 + q * 8;

    floatx4 acc[4][2];
#pragma unroll
    for (int t = 0; t < 4; ++t)
#pragma unroll
        for (int u = 0; u < 2; ++u) acc[t][u] = (floatx4){0.f, 0.f, 0.f, 0.f};

    for (int kc = 0; kc < 8; ++kc) {
        // ---- stage 8 slots (1 KB each): slot = slice*16 + t*4 + s2*2 + nh
#pragma unroll
        for (int t = 0; t < 4; ++t)
#pragma unroll
            for (int s2 = 0; s2 < 2; ++s2) {
                const _Float16* gp = Asrc + t * (16 * 1024) + kc * 64 + s2 * 32;
                GLDS16(gp, &As[(slice * 16 + t * 4 + s2 * 2 + nh) * 512]);
            }
        __syncthreads();

#pragma unroll
        for (int s2 = 0; s2 < 2; ++s2) {
            half8 bh[2], bl[2];
#pragma unroll
            for (int u = 0; u < 2; ++u) {
                const _Float16* pb = Wp + (size_t)(by * 4 + nh * 2 + u) * 16384
                                   + (size_t)(slice * 16 + kc * 2 + s2) * 512 + lane * 8;
                bh[u] = *(const half8*)pb;
                bl[u] = *(const half8*)(pb + WOFF);
            }
#pragma unroll
            for (int t = 0; t < 4; ++t) {
                half8 ah = *(const half8*)&As[(slice * 16 + t * 4 + s2 * 2 + 0) * 512 + lane * 8];
                half8 al = *(const half8*)&As[(slice * 16 + t * 4 + s2 * 2 + 1) * 512 + lane * 8];
#pragma unroll
                for (int u = 0; u < 2; ++u) {
                    acc[t][u] = MFMA16(ah, bh[u], acc[t][u]);
                    acc[t][u] = MFMA16(ah, bl[u], acc[t][u]);
                    acc[t][u] = MFMA16(al, bh[u], acc[t][u]);
                }
            }
        }
        __syncthreads();
    }

    // ---- cross-slice reduce + epilogue (C/D: row = q*4+reg, col = r)
    if (slice == 1) {
#pragma unroll
        for (int t = 0; t < 4; ++t)
#pragma unroll
            for (int u = 0; u < 2; ++u)
#pragma unroll
                for (int reg = 0; reg < 4; ++reg)
                    Red[(t * 16 + q * 4 + reg) * 64 + nh * 32 + u * 16 + r]
                        = acc[t][u][reg];
    }
    __syncthreads();
    if (slice == 0) {
#pragma unroll
        for (int t = 0; t < 4; ++t)
#pragma unroll
            for (int u = 0; u < 2; ++u) {
                int col = bn0 + nh * 32 + u * 16 + r;
                float bw = bW[col];
#pragma unroll
                for (int reg = 0; reg < 4; ++reg) {
                    int ml = t * 16 + q * 4 + reg;
                    float v = acc[t][u][reg]
                            + Red[ml * 64 + nh * 32 + u * 16 + r];
                    float x = relu_f(v + bw);
                    _Float16 hi = (_Float16)x;
                    size_t o = (size_t)(bm0 + ml) * EMBED + col;
                    Cp[o] = hi;
                    Cp[o + hoff] = (_Float16)(x - (float)hi);
                }
            }
    }
    __syncthreads();   // protect LDS reuse across fused phases
}

// ---------------------------------------------------------------------------
// 32x32 split-K body (h=3,4; M multiple of 32). grid = (M/32, 16).
__device__ void dev_splitk32(const _Float16* __restrict__ Ap,
                             const _Float16* __restrict__ Wp,
                             const float* __restrict__ bW,
                             _Float16* __restrict__ Cp, int hoff,
                             int bx, int by)
{
    __shared__ float red32[4096];

    int tid = threadIdx.x;
    int wave = tid >> 6, lane = tid & 63;
    int q = lane >> 4, r = lane & 15;
    int m0 = bx * 32, n0 = by * 32;

    const _Float16 *pAh[2], *pAl[2];
#pragma unroll
    for (int mi = 0; mi < 2; ++mi) {
        int m = m0 + mi * 16 + r;
        int prow = 2 * m + (wave >> 1);          // child row in prev level
        int kb = (wave & 1) * 256;               // k-offset within child
        pAh[mi] = Ap + (size_t)prow * EMBED + kb + q * 8;
        pAl[mi] = pAh[mi] + hoff;
    }
    const _Float16* pB[2];
#pragma unroll
    for (int u = 0; u < 2; ++u)
        pB[u] = Wp + (size_t)(by * 2 + u) * 16384
              + (size_t)(wave * 8) * 512 + lane * 8;

    floatx4 acc[2][2];
#pragma unroll
    for (int mi = 0; mi < 2; ++mi)
#pragma unroll
        for (int u = 0; u < 2; ++u) acc[mi][u] = (floatx4){0.f, 0.f, 0.f, 0.f};

#pragma unroll
    for (int s = 0; s < 8; ++s) {
        half8 ah[2], al[2], bh[2], bl[2];
#pragma unroll
        for (int mi = 0; mi < 2; ++mi) {
            ah[mi] = *(const half8*)(pAh[mi] + s * 32);
            al[mi] = *(const half8*)(pAl[mi] + s * 32);
        }
#pragma unroll
        for (int u = 0; u < 2; ++u) {
            bh[u] = *(const half8*)(pB[u] + s * 512);
            bl[u] = *(const half8*)(pB[u] + s * 512 + WOFF);
        }
#pragma unroll
        for (int mi = 0; mi < 2; ++mi)
#pragma unroll
            for (int u = 0; u < 2; ++u) {
                acc[mi][u] = MFMA16(ah[mi], bh[u], acc[mi][u]);
                acc[mi][u] = MFMA16(ah[mi], bl[u], acc[mi][u]);
                acc[mi][u] = MFMA16(al[mi], bh[u], acc[mi][u]);
            }
    }

#pragma unroll
    for (int mi = 0; mi < 2; ++mi)
#pragma unroll
        for (int u = 0; u < 2; ++u)
#pragma unroll
            for (int reg = 0; reg < 4; ++reg)
                red32[wave * 1024 + (mi * 16 + q * 4 + reg) * 32 + u * 16 + r]
                    = acc[mi][u][reg];
    __syncthreads();

    int row = tid >> 3, c4 = (tid & 7) * 4;
    _Float16 hi4[4], lo4[4];
#pragma unroll
    for (int j = 0; j < 4; ++j) {
        int c = row * 32 + c4 + j;
        float v = red32[c] + red32[1024 + c] + red32[2048 + c] + red32[3072 + c];
        float x = relu_f(v + bW[n0 + c4 + j]);
        _Float16 hi = (_Float16)x;
        hi4[j] = hi;
        lo4[j] = (_Float16)(x - (float)hi);
    }
    size_t o = (size_t)(m0 + row) * EMBED + n0 + c4;
#pragma unroll
    for (int j = 0; j < 4; ++j) { Cp[o + j] = hi4[j]; Cp[o + hoff + j] = lo4[j]; }
    __syncthreads();   // protect LDS reuse across fused phases
}

// ---------------------------------------------------------------------------
// 16x16 split-K body (h=5..13). grid = (ceil(M/16), 32).
__device__ void dev_splitk(const _Float16* __restrict__ Ap,
                           const _Float16* __restrict__ Wp,
                           const float* __restrict__ bW,
                           _Float16* __restrict__ Cp, int hoff, int M,
                           int bx, int by)
{
    __shared__ float red16[1024];

    int tid = threadIdx.x;
    int wave = tid >> 6, lane = tid & 63;
    int q = lane >> 4, r = lane & 15;
    int mt = bx, u = by;

    int m = mt * 16 + r;
    if (m >= M) m = M - 1;
    int prow = 2 * m + (wave >> 1);
    int kb = (wave & 1) * 256;
    const _Float16* pAh = Ap + (size_t)prow * EMBED + kb + q * 8;
    const _Float16* pAl = pAh + hoff;
    const _Float16* pB  = Wp + (size_t)u * 16384 + (size_t)(wave * 8) * 512 + lane * 8;

    floatx4 acc = (floatx4){0.f, 0.f, 0.f, 0.f};
#pragma unroll
    for (int s = 0; s < 8; ++s) {
        half8 ah = *(const half8*)(pAh + s * 32);
        half8 al = *(const half8*)(pAl + s * 32);
        half8 bh = *(const half8*)(pB + s * 512);
        half8 bl = *(const half8*)(pB + s * 512 + WOFF);
        acc = MFMA16(ah, bh, acc);
        acc = MFMA16(ah, bl, acc);
        acc = MFMA16(al, bh, acc);
    }
#pragma unroll
    for (int reg = 0; reg < 4; ++reg)
        red16[wave * 256 + (q * 4 + reg) * 16 + r] = acc[reg];
    __syncthreads();

    int row = tid >> 4, col = tid & 15;
    float v = red16[row * 16 + col] + red16[256 + row * 16 + col]
            + red16[512 + row * 16 + col] + red16[768 + row * 16 + col];
    int mm = mt * 16 + row;
    if (mm < M) {
        int colg = u * 16 + col;
        float x = relu_f(v + bW[colg]);
        _Float16 hi = (_Float16)x;
        size_t o = (size_t)mm * EMBED + colg;
        Cp[o] = hi;
        Cp[o + hoff] = (_Float16)(x - (float)hi);
    }
    __syncthreads();   // protect LDS reuse across fused phases
}

// ---------------------------------------------------------------------------
// Projection of one buffer row j (level-major) -> out[idx(h,m)], one wave.
__device__ void dev_out_row(const _Float16* __restrict__ Hh,
                            const _Float16* __restrict__ Hl,
                            const float* __restrict__ P,
                            const float* __restrict__ bP,
                            float* __restrict__ out, int nNodes,
                            int j, int lane)
{
    int v = nNodes - j;                         // 16383 - j >= 1
    int h = 13 - (31 - __clz(v));
    int m = j - ((nNodes + 1) - (1 << (13 - h + 1)));
    int node = ((m + 1) << (h + 1)) - 2 - __popc(m);

    half8 hv = *(const half8*)(Hh + (size_t)j * EMBED + lane * 8);
    half8 lv = *(const half8*)(Hl + (size_t)j * EMBED + lane * 8);
    float hx[8];
#pragma unroll
    for (int k = 0; k < 8; ++k) hx[k] = (float)hv[k] + (float)lv[k];
    float s[5];
#pragma unroll
    for (int c = 0; c < 5; ++c) {
        const float* p = P + c * EMBED + lane * 8;
        float4 p0 = *(const float4*)p;
        float4 p1 = *(const float4*)(p + 4);
        s[c] = hx[0] * p0.x + hx[1] * p0.y + hx[2] * p0.z + hx[3] * p0.w
             + hx[4] * p1.x + hx[5] * p1.y + hx[6] * p1.z + hx[7] * p1.w;
    }
#pragma unroll
    for (int o = 32; o > 0; o >>= 1)
#pragma unroll
        for (int c = 0; c < 5; ++c)
            s[c] += __shfl_down(s[c], o, 64);
    if (lane == 0) {
#pragma unroll
        for (int c = 0; c < 5; ++c)
            out[(size_t)node * 5 + c] = s[c] + bP[c];
    }
}

// ---------------------------------------------------------------------------
// THE fused cooperative kernel: packleaf + 13 levels + projection, grid.sync
// between phases. 512 blocks x 256 threads; 68 KB LDS -> 2 blocks/CU.
__global__ __launch_bounds__(256, 2)
void fused_all(const int* __restrict__ word, const float* __restrict__ emb,
               const float* __restrict__ W, const float* __restrict__ bW,
               const float* __restrict__ P, const float* __restrict__ bP,
               _Float16* __restrict__ Whp, _Float16* __restrict__ Hh,
               _Float16* __restrict__ Hl, float* __restrict__ out,
               int nNodes)
{
    cg::grid_group grid = cg::this_grid();
    int bid = blockIdx.x;
    int nRows = nNodes + 1;                     // 16384
    int nLeaves = nRows / 2;                    // 8192
    int hoff = nRows * EMBED;

    // phase 0: pack W + leaves (256 active blocks)
    if (bid < 256)
        dev_packleaf(W, emb, word, Whp, Hh, Hl, nLeaves, bid);
    grid.sync();

    // levels 1..2: 64x64 staged GEMM. grid (M/64, 8), x-fastest.
    for (int h = 1; h <= 2; ++h) {
        const _Float16* Ap = Hh + (size_t)(nRows - (1 << (14 - (h - 1)))) * EMBED;
        _Float16*       Cp = Hh + (size_t)(nRows - (1 << (14 - h))) * EMBED;
        int lg = 13 - h - 6;                    // log2(M/64): 6, 5
        int nb = (1 << lg) * 8;
        if (bid < nb)
            dev_gemm_lvl(Ap, Whp, bW, Cp, hoff,
                         bid & ((1 << lg) - 1), bid >> lg);
        grid.sync();
    }
    // levels 3..4: 32x32 split-K. grid (M/32, 16).
    for (int h = 3; h <= 4; ++h) {
        const _Float16* Ap = Hh + (size_t)(nRows - (1 << (14 - (h - 1)))) * EMBED;
        _Float16*       Cp = Hh + (size_t)(nRows - (1 << (14 - h))) * EMBED;
        int lg = 13 - h - 5;                    // log2(M/32): 5, 4
        int nb = (1 << lg) * 16;
        if (bid < nb)
            dev_splitk32(Ap, Whp, bW, Cp, hoff,
                         bid & ((1 << lg) - 1), bid >> lg);
        grid.sync();
    }
    // levels 5..13: 16x16 split-K. grid (ceil(M/16), 32).
    for (int h = 5; h <= 13; ++h) {
        int M = 1 << (13 - h);
        const _Float16* Ap = Hh + (size_t)(nRows - (1 << (14 - (h - 1)))) * EMBED;
        _Float16*       Cp = Hh + (size_t)(nRows - (1 << (14 - h))) * EMBED;
        int lg = 13 - h - 4;                    // log2(M/16), clamp at 0
        if (lg < 0) lg = 0;
        int nb = (1 << lg) * 32;
        if (bid < nb)
            dev_splitk(Ap, Whp, bW, Cp, hoff, M,
                       bid & ((1 << lg) - 1), bid >> lg);
        grid.sync();
    }
    // projection: 2048 waves, 8 rows each
    int lane = threadIdx.x & 63;
    int gw = bid * 4 + (threadIdx.x >> 6);
    for (int j = gw; j < nNodes; j += 512 * 4)
        dev_out_row(Hh, Hl, P, bP, out, nNodes, j, lane);
}

// ---------------------------------------------------------------------------
// Fallback standalone kernels (original 15-launch path), thin wrappers.
__global__ __launch_bounds__(256)
void packleaf(const float* __restrict__ W, const float* __restrict__ emb,
              const int* __restrict__ word,
              _Float16* __restrict__ Whp,
              _Float16* __restrict__ Hh, _Float16* __restrict__ Hl,
              int nLeaves)
{
    dev_packleaf(W, emb, word, Whp, Hh, Hl, nLeaves, blockIdx.x);
}

__global__ __launch_bounds__(256)
void gemm_lvl(const _Float16* __restrict__ Ap, const _Float16* __restrict__ Wp,
              const float* __restrict__ bW,
              _Float16* __restrict__ Cp, int hoff)
{
    dev_gemm_lvl(Ap, Wp, bW, Cp, hoff, blockIdx.x, blockIdx.y);
}

__global__ __launch_bounds__(256)
void gemm_splitk32(const _Float16* __restrict__ Ap, const _Float16* __restrict__ Wp,
                   const float* __restrict__ bW,
                   _Float16* __restrict__ Cp, int hoff)
{
    dev_splitk32(Ap, Wp, bW, Cp, hoff, blockIdx.x, blockIdx.y);
}

__global__ __launch_bounds__(256)
void gemm_splitk(const _Float16* __restrict__ Ap, const _Float16* __restrict__ Wp,
                 const float* __restrict__ bW,
                 _Float16* __restrict__ Cp, int hoff, int M)
{
    dev_splitk(Ap, Wp, bW, Cp, hoff, M, blockIdx.x, blockIdx.y);
}

__global__ __launch_bounds__(256)
void out_kernel(const _Float16* __restrict__ Hh, const _Float16* __restrict__ Hl,
                const float* __restrict__ P, const float* __restrict__ bP,
                float* __restrict__ out, int nNodes)
{
    int t = blockIdx.x * 256 + threadIdx.x;
    int j = t >> 6, lane = t & 63;
    if (j >= nNodes) return;
    dev_out_row(Hh, Hl, P, bP, out, nNodes, j, lane);
}

// ---------------------------------------------------------------------------
extern "C" void kernel_launch(void* const* d_in, const int* in_sizes, int n_in,
                              void* d_out, int out_size, void* d_ws, size_t ws_size,
                              hipStream_t stream)
{
    const int*   word = (const int*)d_in[1];
    const float* emb  = (const float*)d_in[4];
    const float* W    = (const float*)d_in[5];
    const float* bW   = (const float*)d_in[6];
    const float* P    = (const float*)d_in[7];
    const float* bP   = (const float*)d_in[8];
    float* out = (float*)d_out;

    int nNodes  = in_sizes[0];            // 16383
    int nLeaves = (nNodes + 1) / 2;       // 8192
    int nRows   = nNodes + 1;             // 16384

    int hoff = nRows * EMBED;             // halves between Hh and Hl
    _Float16* Hh  = (_Float16*)d_ws;
    _Float16* Hl  = Hh + hoff;
    _Float16* Whp = Hl + hoff;            // hi; lo at +WOFF

    // ---- preferred: single cooperative launch
    {
        void* kargs[] = {
            (void*)&word, (void*)&emb, (void*)&W, (void*)&bW,
            (void*)&P, (void*)&bP, (void*)&Whp, (void*)&Hh,
            (void*)&Hl, (void*)&out, (void*)&nNodes
        };
        hipError_t ce = hipLaunchCooperativeKernel(
            reinterpret_cast<const void*>(&fused_all),
            dim3(512), dim3(256), kargs, 0, stream);
        if (ce == hipSuccess) return;
        (void)hipGetLastError();          // clear, fall through to legacy path
    }

    // ---- fallback: original 15-launch path
    auto roff = [&](int h) { return nRows - (1 << (14 - h)); };

    packleaf<<<dim3(256), dim3(256), 0, stream>>>(
        W, emb, word, Whp, Hh, Hl, nLeaves);

    for (int h = 1; h <= 2; ++h) {        // M = 4096, 2048
        int M = 1 << (13 - h);
        gemm_lvl<<<dim3(M / 64, 8), dim3(256), 0, stream>>>(
            Hh + (size_t)roff(h - 1) * EMBED, Whp, bW,
            Hh + (size_t)roff(h) * EMBED, hoff);
    }
    for (int h = 3; h <= 4; ++h) {        // M = 1024, 512
        int M = 1 << (13 - h);
        gemm_splitk32<<<dim3(M / 32, 16), dim3(256), 0, stream>>>(
            Hh + (size_t)roff(h - 1) * EMBED, Whp, bW,
            Hh + (size_t)roff(h) * EMBED, hoff);
    }
    for (int h = 5; h <= 13; ++h) {       // M = 256..1
        int M = 1 << (13 - h);
        gemm_splitk<<<dim3((M + 15) / 16, 32), dim3(256), 0, stream>>>(
            Hh + (size_t)roff(h - 1) * EMBED, Whp, bW,
            Hh + (size_t)roff(h) * EMBED, hoff, M);
    }
    out_kernel<<<dim3((nNodes * 64 + 255) / 256), dim3(256), 0, stream>>>(
        Hh, Hl, P, bP, out, nNodes);
}

// Round 2
// 290.255 us; speedup vs baseline: 3.4915x; 3.4915x over previous
//
#include <hip/hip_runtime.h>

// RecursiveNN, perfect binary tree, 8192 leaves, EMBED=512.
// LEVEL-MAJOR H layout: level h stored as dense [M_h][512] at row offset
// roff(h) = 16384 - 2^(14-h). Children of (h,m) are (h-1,2m),(h-1,2m+1), so
// level h's GEMM input [M][1024] is EXACTLY the previous level's buffer —
// no gather, no tree indexing in hot loops. Post-order node id (for the final
// scatter only): idx(h,m) = ((m+1)<<(h+1)) - 2 - popc(m).
// Numerics: fp16 hi+lo split H and W, 3-term MFMA (hh,hl,lh) => fp32-level.
//
// SYNC LESSON (r1): cooperative grid.sync costs ~50us PER SYNC on 8-XCD
// MI355X (16 syncs -> 900us kernel). Kernel boundaries (~2-4us in graph)
// are the cheap sync primitive. Multi-launch is the right structure.
//
// r2 (this): h=1,2 move from 64x64 split-K tiles to 128x128 / 128x64
// non-split tiles: halves A re-reads (col-tiles 8->4) and B re-reads
// (row-tiles 64->32 for h=1), kills the Red-LDS cross-slice reduce.
// Staging is WAVE-PRIVATE (each wave stages the 8 fragment slots for its
// own 32 rows) -> zero __syncthreads in the whole kernel; double-buffered
// slots with s_waitcnt vmcnt(8) software pipeline.

#define EMBED 512
#define K2    1024
#define WOFF  (EMBED * K2)

typedef _Float16 half8 __attribute__((ext_vector_type(8)));
typedef float    floatx4 __attribute__((ext_vector_type(4)));

__device__ __forceinline__ float relu_f(float x) { return fmaxf(x, 0.0f); }

#define GLDS16(gp, lp)                                                        \
    __builtin_amdgcn_global_load_lds(                                         \
        (const __attribute__((address_space(1))) void*)(gp),                  \
        (__attribute__((address_space(3))) void*)(lp), 16, 0, 0)

#define MFMA16(a, b, c) __builtin_amdgcn_mfma_f32_16x16x32_f16(a, b, c, 0, 0, 0)

// ---------------------------------------------------------------------------
// pack W into fp16 hi/lo MFMA-B fragment order + leaves into level-0 rows.
__global__ __launch_bounds__(256)
void packleaf(const float* __restrict__ W, const float* __restrict__ emb,
              const int* __restrict__ word,
              _Float16* __restrict__ Whp,       // lo at +WOFF
              _Float16* __restrict__ Hh, _Float16* __restrict__ Hl,
              int nLeaves)
{
    int tid = threadIdx.x;
    int wave = tid >> 6, lane = tid & 63;

    {   // ---- pack W: 65536 jobs = 256 blocks x 256 threads
        int t = blockIdx.x * 256 + tid;
        int n = t >> 7, kc = t & 127;
        const float* src = W + (size_t)n * K2 + kc * 8;
        int s = kc >> 2, quad = kc & 3;
        int ln = (quad << 4) | (n & 15);
        size_t off = (size_t)(n >> 4) * 16384 + (size_t)s * 512 + (size_t)ln * 8;
        half8 hi, lo;
#pragma unroll
        for (int j = 0; j < 8; ++j) {
            float w = src[j];
            _Float16 h16 = (_Float16)w;
            hi[j] = h16;
            lo[j] = (_Float16)(w - (float)h16);
        }
        *(half8*)(Whp + off) = hi;
        *(half8*)(Whp + WOFF + off) = lo;
    }
    {   // ---- leaves -> level-0 rows (m-order, coalesced)
#pragma unroll
        for (int i = 0; i < 8; ++i) {
            int m = blockIdx.x * 32 + wave * 8 + i;
            if (m < nLeaves) {
                int wd = word[2 * m - __popc(m)];    // post-order leaf id
                const float4* src = (const float4*)(emb + (size_t)wd * EMBED) + lane * 2;
                float4 a = src[0], b = src[1];
                float v[8] = {a.x, a.y, a.z, a.w, b.x, b.y, b.z, b.w};
                half8 hi, lo;
#pragma unroll
                for (int j = 0; j < 8; ++j) {
                    float x = relu_f(v[j]);
                    _Float16 h16 = (_Float16)x;
                    hi[j] = h16;
                    lo[j] = (_Float16)(x - (float)h16);
                }
                *(half8*)(Hh + (size_t)m * EMBED + lane * 8) = hi;
                *(half8*)(Hl + (size_t)m * EMBED + lane * 8) = lo;
            }
        }
    }
}

// ---------------------------------------------------------------------------
// Big-tile level GEMM for h=1,2. BM=128 rows, BN=BNF*16 cols, 4 waves.
// Wave w owns rows [w*32, w*32+32) (t = 2w+t2) x ALL BN cols. Full K=1024
// serial per block (NO split-K, no cross-wave reduce). Each wave stages its
// own rows' A fragments into wave-private LDS slots -> NO __syncthreads
// anywhere; double-buffered slots + s_waitcnt vmcnt(8) pipeline.
// Slot (buf,w,t2,s2,hl): 512 halves, lane(q,r) = A[bm0+(2w+t2)*16+r]
//                        [kc*64 + s2*32 + q*8 ..+8], hl selects hi/lo.
template <int BNF>
__global__ __launch_bounds__(256, 2)
void gemm_big(const _Float16* __restrict__ Ap,  // prev level base hi (lo at +hoff)
              const _Float16* __restrict__ Wp,  // Whp (lo at +WOFF)
              const float* __restrict__ bW,
              _Float16* __restrict__ Cp,        // cur level base hi (lo at +hoff)
              int hoff)
{
    __shared__ _Float16 As[32768];              // 64 KB: 2 bufs x 32 slots x 1 KB

    int tid = threadIdx.x;
    int w = tid >> 6, lane = tid & 63;
    int q = lane >> 4, r = lane & 15;
    int bm0 = blockIdx.x * 128;
    int bn0 = blockIdx.y * (BNF * 16);

    // per-lane global source row base (row = bm0 + w*32 + t2*16 + r)
    const _Float16* Asrc = Ap + (size_t)(bm0 + w * 32 + r) * 1024 + q * 8;

    floatx4 acc[2][BNF];
#pragma unroll
    for (int t2 = 0; t2 < 2; ++t2)
#pragma unroll
        for (int u = 0; u < BNF; ++u) acc[t2][u] = (floatx4){0.f, 0.f, 0.f, 0.f};

    // ---- stage chunk 0 into buf 0
#pragma unroll
    for (int t2 = 0; t2 < 2; ++t2)
#pragma unroll
        for (int s2 = 0; s2 < 2; ++s2)
#pragma unroll
            for (int hl = 0; hl < 2; ++hl) {
                const _Float16* gp = Asrc + (size_t)hl * hoff
                                   + t2 * (16 * 1024) + s2 * 32;
                GLDS16(gp, &As[(((w * 2 + t2) * 2 + s2) * 2 + hl) * 512]);
            }

    for (int kc = 0; kc < 16; ++kc) {
        int buf = kc & 1;
        // ---- prefetch chunk kc+1 into the other buffer
        if (kc < 15) {
#pragma unroll
            for (int t2 = 0; t2 < 2; ++t2)
#pragma unroll
                for (int s2 = 0; s2 < 2; ++s2)
#pragma unroll
                    for (int hl = 0; hl < 2; ++hl) {
                        const _Float16* gp = Asrc + (size_t)hl * hoff
                                           + t2 * (16 * 1024) + (kc + 1) * 64 + s2 * 32;
                        GLDS16(gp, &As[((buf ^ 1) * 32
                                        + ((w * 2 + t2) * 2 + s2) * 2 + hl) * 512]);
                    }
            asm volatile("s_waitcnt vmcnt(8)" ::: "memory");
        } else {
            asm volatile("s_waitcnt vmcnt(0)" ::: "memory");
        }

        // ---- compute chunk kc from buf
#pragma unroll
        for (int s2 = 0; s2 < 2; ++s2) {
            half8 ah[2], al[2];
#pragma unroll
            for (int t2 = 0; t2 < 2; ++t2) {
                int slot = buf * 32 + ((w * 2 + t2) * 2 + s2) * 2;
                ah[t2] = *(const half8*)&As[slot * 512 + lane * 8];
                al[t2] = *(const half8*)&As[(slot + 1) * 512 + lane * 8];
            }
#pragma unroll
            for (int u = 0; u < BNF; ++u) {
                const _Float16* pb = Wp + (size_t)(blockIdx.y * BNF + u) * 16384
                                   + (size_t)(kc * 2 + s2) * 512 + lane * 8;
                half8 bh = *(const half8*)pb;
                half8 bl = *(const half8*)(pb + WOFF);
#pragma unroll
                for (int t2 = 0; t2 < 2; ++t2) {
                    acc[t2][u] = MFMA16(ah[t2], bh, acc[t2][u]);
                    acc[t2][u] = MFMA16(ah[t2], bl, acc[t2][u]);
                    acc[t2][u] = MFMA16(al[t2], bh, acc[t2][u]);
                }
            }
        }
    }

    // ---- epilogue: bias + relu + hi/lo split (C/D: row = q*4+reg, col = r)
#pragma unroll
    for (int t2 = 0; t2 < 2; ++t2)
#pragma unroll
        for (int u = 0; u < BNF; ++u) {
            int col = bn0 + u * 16 + r;
            float bw = bW[col];
#pragma unroll
            for (int reg = 0; reg < 4; ++reg) {
                int row = bm0 + (w * 2 + t2) * 16 + q * 4 + reg;
                float x = relu_f(acc[t2][u][reg] + bw);
                _Float16 hi = (_Float16)x;
                size_t o = (size_t)row * EMBED + col;
                Cp[o] = hi;
                Cp[o + hoff] = (_Float16)(x - (float)hi);
            }
        }
}

// ---------------------------------------------------------------------------
// 32x32 split-K kernel (h=3,4; M multiple of 32). grid = (M/32, 16).
__global__ __launch_bounds__(256)
void gemm_splitk32(const _Float16* __restrict__ Ap, const _Float16* __restrict__ Wp,
                   const float* __restrict__ bW,
                   _Float16* __restrict__ Cp, int hoff)
{
    __shared__ float red[4096];

    int tid = threadIdx.x;
    int wave = tid >> 6, lane = tid & 63;
    int q = lane >> 4, r = lane & 15;
    int m0 = blockIdx.x * 32, n0 = blockIdx.y * 32;

    const _Float16 *pAh[2], *pAl[2];
#pragma unroll
    for (int mi = 0; mi < 2; ++mi) {
        int m = m0 + mi * 16 + r;
        int prow = 2 * m + (wave >> 1);          // child row in prev level
        int kb = (wave & 1) * 256;               // k-offset within child
        pAh[mi] = Ap + (size_t)prow * EMBED + kb + q * 8;
        pAl[mi] = pAh[mi] + hoff;
    }
    const _Float16* pB[2];
#pragma unroll
    for (int u = 0; u < 2; ++u)
        pB[u] = Wp + (size_t)(blockIdx.y * 2 + u) * 16384
              + (size_t)(wave * 8) * 512 + lane * 8;

    floatx4 acc[2][2];
#pragma unroll
    for (int mi = 0; mi < 2; ++mi)
#pragma unroll
        for (int u = 0; u < 2; ++u) acc[mi][u] = (floatx4){0.f, 0.f, 0.f, 0.f};

#pragma unroll
    for (int s = 0; s < 8; ++s) {
        half8 ah[2], al[2], bh[2], bl[2];
#pragma unroll
        for (int mi = 0; mi < 2; ++mi) {
            ah[mi] = *(const half8*)(pAh[mi] + s * 32);
            al[mi] = *(const half8*)(pAl[mi] + s * 32);
        }
#pragma unroll
        for (int u = 0; u < 2; ++u) {
            bh[u] = *(const half8*)(pB[u] + s * 512);
            bl[u] = *(const half8*)(pB[u] + s * 512 + WOFF);
        }
#pragma unroll
        for (int mi = 0; mi < 2; ++mi)
#pragma unroll
            for (int u = 0; u < 2; ++u) {
                acc[mi][u] = MFMA16(ah[mi], bh[u], acc[mi][u]);
                acc[mi][u] = MFMA16(ah[mi], bl[u], acc[mi][u]);
                acc[mi][u] = MFMA16(al[mi], bh[u], acc[mi][u]);
            }
    }

#pragma unroll
    for (int mi = 0; mi < 2; ++mi)
#pragma unroll
        for (int u = 0; u < 2; ++u)
#pragma unroll
            for (int reg = 0; reg < 4; ++reg)
                red[wave * 1024 + (mi * 16 + q * 4 + reg) * 32 + u * 16 + r]
                    = acc[mi][u][reg];
    __syncthreads();

    int row = tid >> 3, c4 = (tid & 7) * 4;
    _Float16 hi4[4], lo4[4];
#pragma unroll
    for (int j = 0; j < 4; ++j) {
        int c = row * 32 + c4 + j;
        float v = red[c] + red[1024 + c] + red[2048 + c] + red[3072 + c];
        float x = relu_f(v + bW[n0 + c4 + j]);
        _Float16 hi = (_Float16)x;
        hi4[j] = hi;
        lo4[j] = (_Float16)(x - (float)hi);
    }
    size_t o = (size_t)(m0 + row) * EMBED + n0 + c4;
#pragma unroll
    for (int j = 0; j < 4; ++j) { Cp[o + j] = hi4[j]; Cp[o + hoff + j] = lo4[j]; }
}

// ---------------------------------------------------------------------------
// 16x16 split-K kernel (h=5..13). grid = (ceil(M/16), 32).
__global__ __launch_bounds__(256)
void gemm_splitk(const _Float16* __restrict__ Ap, const _Float16* __restrict__ Wp,
                 const float* __restrict__ bW,
                 _Float16* __restrict__ Cp, int hoff, int M)
{
    __shared__ float red[1024];

    int tid = threadIdx.x;
    int wave = tid >> 6, lane = tid & 63;
    int q = lane >> 4, r = lane & 15;
    int mt = blockIdx.x, u = blockIdx.y;

    int m = mt * 16 + r;
    if (m >= M) m = M - 1;
    int prow = 2 * m + (wave >> 1);
    int kb = (wave & 1) * 256;
    const _Float16* pAh = Ap + (size_t)prow * EMBED + kb + q * 8;
    const _Float16* pAl = pAh + hoff;
    const _Float16* pB  = Wp + (size_t)u * 16384 + (size_t)(wave * 8) * 512 + lane * 8;

    floatx4 acc = (floatx4){0.f, 0.f, 0.f, 0.f};
#pragma unroll
    for (int s = 0; s < 8; ++s) {
        half8 ah = *(const half8*)(pAh + s * 32);
        half8 al = *(const half8*)(pAl + s * 32);
        half8 bh = *(const half8*)(pB + s * 512);
        half8 bl = *(const half8*)(pB + s * 512 + WOFF);
        acc = MFMA16(ah, bh, acc);
        acc = MFMA16(ah, bl, acc);
        acc = MFMA16(al, bh, acc);
    }
#pragma unroll
    for (int reg = 0; reg < 4; ++reg)
        red[wave * 256 + (q * 4 + reg) * 16 + r] = acc[reg];
    __syncthreads();

    int row = tid >> 4, col = tid & 15;
    float v = red[row * 16 + col] + red[256 + row * 16 + col]
            + red[512 + row * 16 + col] + red[768 + row * 16 + col];
    int mm = mt * 16 + row;
    if (mm < M) {
        int colg = u * 16 + col;
        float x = relu_f(v + bW[colg]);
        _Float16 hi = (_Float16)x;
        size_t o = (size_t)mm * EMBED + colg;
        Cp[o] = hi;
        Cp[o + hoff] = (_Float16)(x - (float)hi);
    }
}

// ---------------------------------------------------------------------------
// Projection: buffer row j (level-major) -> out[idx(h,m)]. Level decode:
// h = 13 - floor(log2(16383 - j)), m = j - (16384 - 2^(14-h)).
__global__ __launch_bounds__(256)
void out_kernel(const _Float16* __restrict__ Hh, const _Float16* __restrict__ Hl,
                const float* __restrict__ P, const float* __restrict__ bP,
                float* __restrict__ out, int nNodes)
{
    int t = blockIdx.x * 256 + threadIdx.x;
    int j = t >> 6, lane = t & 63;
    if (j >= nNodes) return;
    int v = nNodes - j;                         // 16383 - j >= 1
    int h = 13 - (31 - __clz(v));
    int m = j - ((nNodes + 1) - (1 << (13 - h + 1)));
    int node = ((m + 1) << (h + 1)) - 2 - __popc(m);

    half8 hv = *(const half8*)(Hh + (size_t)j * EMBED + lane * 8);
    half8 lv = *(const half8*)(Hl + (size_t)j * EMBED + lane * 8);
    float hx[8];
#pragma unroll
    for (int k = 0; k < 8; ++k) hx[k] = (float)hv[k] + (float)lv[k];
    float s[5];
#pragma unroll
    for (int c = 0; c < 5; ++c) {
        const float* p = P + c * EMBED + lane * 8;
        float4 p0 = *(const float4*)p;
        float4 p1 = *(const float4*)(p + 4);
        s[c] = hx[0] * p0.x + hx[1] * p0.y + hx[2] * p0.z + hx[3] * p0.w
             + hx[4] * p1.x + hx[5] * p1.y + hx[6] * p1.z + hx[7] * p1.w;
    }
#pragma unroll
    for (int o = 32; o > 0; o >>= 1)
#pragma unroll
        for (int c = 0; c < 5; ++c)
            s[c] += __shfl_down(s[c], o, 64);
    if (lane == 0) {
#pragma unroll
        for (int c = 0; c < 5; ++c)
            out[(size_t)node * 5 + c] = s[c] + bP[c];
    }
}

// ---------------------------------------------------------------------------
extern "C" void kernel_launch(void* const* d_in, const int* in_sizes, int n_in,
                              void* d_out, int out_size, void* d_ws, size_t ws_size,
                              hipStream_t stream)
{
    const int*   word = (const int*)d_in[1];
    const float* emb  = (const float*)d_in[4];
    const float* W    = (const float*)d_in[5];
    const float* bW   = (const float*)d_in[6];
    const float* P    = (const float*)d_in[7];
    const float* bP   = (const float*)d_in[8];
    float* out = (float*)d_out;

    int nNodes  = in_sizes[0];            // 16383
    int nLeaves = (nNodes + 1) / 2;       // 8192
    int nRows   = nNodes + 1;             // 16384

    int hoff = nRows * EMBED;             // halves between Hh and Hl
    _Float16* Hh  = (_Float16*)d_ws;
    _Float16* Hl  = Hh + hoff;
    _Float16* Whp = Hl + hoff;            // hi; lo at +WOFF

    // level row offsets: roff(h) = 16384 - 2^(14-h)
    auto roff = [&](int h) { return nRows - (1 << (14 - h)); };

    packleaf<<<dim3(256), dim3(256), 0, stream>>>(
        W, emb, word, Whp, Hh, Hl, nLeaves);

    // h=1: M=4096, 128x128 tiles -> grid (32,4)
    gemm_big<8><<<dim3(32, 4), dim3(256), 0, stream>>>(
        Hh + (size_t)roff(0) * EMBED, Whp, bW,
        Hh + (size_t)roff(1) * EMBED, hoff);
    // h=2: M=2048, 128x64 tiles -> grid (16,8)
    gemm_big<4><<<dim3(16, 8), dim3(256), 0, stream>>>(
        Hh + (size_t)roff(1) * EMBED, Whp, bW,
        Hh + (size_t)roff(2) * EMBED, hoff);

    for (int h = 3; h <= 4; ++h) {        // M = 1024, 512
        int M = 1 << (13 - h);
        gemm_splitk32<<<dim3(M / 32, 16), dim3(256), 0, stream>>>(
            Hh + (size_t)roff(h - 1) * EMBED, Whp, bW,
            Hh + (size_t)roff(h) * EMBED, hoff);
    }
    for (int h = 5; h <= 13; ++h) {       // M = 256..1
        int M = 1 << (13 - h);
        gemm_splitk<<<dim3((M + 15) / 16, 32), dim3(256), 0, stream>>>(
            Hh + (size_t)roff(h - 1) * EMBED, Whp, bW,
            Hh + (size_t)roff(h) * EMBED, hoff, M);
    }
    out_kernel<<<dim3((nNodes * 64 + 255) / 256), dim3(256), 0, stream>>>(
        Hh, Hl, P, bP, out, nNodes);
}

// Round 3
// 256.726 us; speedup vs baseline: 3.9475x; 1.1306x over previous
//
#include <hip/hip_runtime.h>

// RecursiveNN, perfect binary tree, 8192 leaves, EMBED=512.
// LEVEL-MAJOR H layout: level h stored as dense [M_h][512] at row offset
// roff(h) = 16384 - 2^(14-h). Children of (h,m) are (h-1,2m),(h-1,2m+1), so
// level h's GEMM input [M][1024] is EXACTLY the previous level's buffer —
// no gather, no tree indexing in hot loops. Post-order node id (for the final
// scatter only): idx(h,m) = ((m+1)<<(h+1)) - 2 - popc(m).
// Numerics: fp16 hi+lo split H and W, 3-term MFMA (hh,hl,lh) => fp32-level.
//
// SYNC LESSON (r1): cooperative grid.sync costs ~50us PER SYNC on 8-XCD
// MI355X (16 syncs -> 900us). Kernel boundaries are the cheap sync.
// LATENCY LESSON (r2): small grids (128 blocks) + direct-from-L2 B loads in
// the MFMA dep chain + 4 waves/block => latency-bound collapse (64us, 7%
// MfmaUtil). Keep >=256 blocks, 8 waves/CU, staged A, barriers.
// OVERHEAD MODEL (r0/r1/r2 fit): ~110us fixed harness overhead (256MB
// poison fill ~40us + launch costs); kernel work ~165us. Levers = per-kernel
// traffic. Tail fusion is dead: any full-width block must stream the whole
// 2MB packed W per level at the ~55B/cyc per-CU L2 floor.
//
// r3 (this): h=1,2 -> gemm_lvl2: same dataflow as the proven 64x64 split-K2
// kernel but BM=128 with 512-thread/8-wave blocks. Halves B-traffic
// (row-tiles 64->32): h1 256->192MB, h2 128->96MB. Per-slice K order
// bit-identical to r0 => absmax unchanged.

#define EMBED 512
#define K2    1024
#define WOFF  (EMBED * K2)

typedef _Float16 half8 __attribute__((ext_vector_type(8)));
typedef float    floatx4 __attribute__((ext_vector_type(4)));

__device__ __forceinline__ float relu_f(float x) { return fmaxf(x, 0.0f); }

#define GLDS16(gp, lp)                                                        \
    __builtin_amdgcn_global_load_lds(                                         \
        (const __attribute__((address_space(1))) void*)(gp),                  \
        (__attribute__((address_space(3))) void*)(lp), 16, 0, 0)

#define MFMA16(a, b, c) __builtin_amdgcn_mfma_f32_16x16x32_f16(a, b, c, 0, 0, 0)

// ---------------------------------------------------------------------------
// pack W into fp16 hi/lo MFMA-B fragment order + leaves into level-0 rows.
__global__ __launch_bounds__(256)
void packleaf(const float* __restrict__ W, const float* __restrict__ emb,
              const int* __restrict__ word,
              _Float16* __restrict__ Whp,       // lo at +WOFF
              _Float16* __restrict__ Hh, _Float16* __restrict__ Hl,
              int nLeaves)
{
    int tid = threadIdx.x;
    int wave = tid >> 6, lane = tid & 63;

    {   // ---- pack W: 65536 jobs = 256 blocks x 256 threads
        int t = blockIdx.x * 256 + tid;
        int n = t >> 7, kc = t & 127;
        const float* src = W + (size_t)n * K2 + kc * 8;
        int s = kc >> 2, quad = kc & 3;
        int ln = (quad << 4) | (n & 15);
        size_t off = (size_t)(n >> 4) * 16384 + (size_t)s * 512 + (size_t)ln * 8;
        half8 hi, lo;
#pragma unroll
        for (int j = 0; j < 8; ++j) {
            float w = src[j];
            _Float16 h16 = (_Float16)w;
            hi[j] = h16;
            lo[j] = (_Float16)(w - (float)h16);
        }
        *(half8*)(Whp + off) = hi;
        *(half8*)(Whp + WOFF + off) = lo;
    }
    {   // ---- leaves -> level-0 rows (m-order, coalesced)
#pragma unroll
        for (int i = 0; i < 8; ++i) {
            int m = blockIdx.x * 32 + wave * 8 + i;
            if (m < nLeaves) {
                int wd = word[2 * m - __popc(m)];    // post-order leaf id
                const float4* src = (const float4*)(emb + (size_t)wd * EMBED) + lane * 2;
                float4 a = src[0], b = src[1];
                float v[8] = {a.x, a.y, a.z, a.w, b.x, b.y, b.z, b.w};
                half8 hi, lo;
#pragma unroll
                for (int j = 0; j < 8; ++j) {
                    float x = relu_f(v[j]);
                    _Float16 h16 = (_Float16)x;
                    hi[j] = h16;
                    lo[j] = (_Float16)(x - (float)h16);
                }
                *(half8*)(Hh + (size_t)m * EMBED + lane * 8) = hi;
                *(half8*)(Hl + (size_t)m * EMBED + lane * 8) = lo;
            }
        }
    }
}

// ---------------------------------------------------------------------------
// Level GEMM for h=1,2. BM=128 rows x BN=64 cols, 512 threads = 8 waves:
// slice = wave&1 (K-half = child), rowq = wave>>1 (32-row quadrant).
// Per BK=64 chunk: A staged via global_load_lds (per-lane row gather on the
// global side) into fragment-order LDS slots -> conflict-free ds reads.
// B direct from packed-fragment global (L2/L1-resident; the 4 rowq waves of
// a slice share the same 16KB/chunk B working set via L1).
// Cross-slice fp32 reduce via Red LDS, fused bias+relu+hi/lo epilogue.
// Per-slice K order identical to the r0 64x64 kernel => bit-identical C.
__global__ __launch_bounds__(512, 1)
void gemm_lvl2(const _Float16* __restrict__ Ap,  // prev level base hi (lo at +hoff)
               const _Float16* __restrict__ Wp,  // Whp (lo at +WOFF)
               const float* __restrict__ bW,
               _Float16* __restrict__ Cp,        // cur level base hi (lo at +hoff)
               int hoff)
{
    __shared__ _Float16 As[32768];              // 64 KB: 64 fragment slots x 512 halves
    __shared__ float Red[8192];                 // 32 KB: 128x64 fp32

    int tid = threadIdx.x;
    int w = tid >> 6, lane = tid & 63;
    int q = lane >> 4, r = lane & 15;
    int slice = w & 1, rowq = w >> 1;           // rowq 0..3
    int bm0 = blockIdx.x * 128, bn0 = blockIdx.y * 64;

    // slot(slice, rg, s2, hl) = ((slice*8 + rg)*2 + s2)*2 + hl, 512 halves each.
    // Wave (slice,rowq) stages rg = rowq*2 + t2 for t2,s2,hl -> 8 slots/chunk.
    floatx4 acc[2][4];
#pragma unroll
    for (int t2 = 0; t2 < 2; ++t2)
#pragma unroll
        for (int u = 0; u < 4; ++u) acc[t2][u] = (floatx4){0.f, 0.f, 0.f, 0.f};

    for (int kc = 0; kc < 8; ++kc) {
        // ---- stage 8 slots (1 KB each) for this wave
#pragma unroll
        for (int t2 = 0; t2 < 2; ++t2)
#pragma unroll
            for (int s2 = 0; s2 < 2; ++s2)
#pragma unroll
                for (int hl = 0; hl < 2; ++hl) {
                    int rg = rowq * 2 + t2;
                    const _Float16* gp = Ap + (size_t)(hl ? hoff : 0)
                                       + (size_t)(bm0 + rg * 16 + r) * 1024
                                       + slice * 512 + kc * 64 + s2 * 32 + q * 8;
                    GLDS16(gp, &As[(((slice * 8 + rg) * 2 + s2) * 2 + hl) * 512]);
                }
        __syncthreads();

#pragma unroll
        for (int s2 = 0; s2 < 2; ++s2) {
            half8 ah[2], al[2];
#pragma unroll
            for (int t2 = 0; t2 < 2; ++t2) {
                int sb = ((slice * 8 + rowq * 2 + t2) * 2 + s2) * 2;
                ah[t2] = *(const half8*)&As[sb * 512 + lane * 8];
                al[t2] = *(const half8*)&As[(sb + 1) * 512 + lane * 8];
            }
#pragma unroll
            for (int u = 0; u < 4; ++u) {
                const _Float16* pb = Wp + (size_t)(blockIdx.y * 4 + u) * 16384
                                   + (size_t)(slice * 16 + kc * 2 + s2) * 512 + lane * 8;
                half8 bh = *(const half8*)pb;
                half8 bl = *(const half8*)(pb + WOFF);
#pragma unroll
                for (int t2 = 0; t2 < 2; ++t2) {
                    acc[t2][u] = MFMA16(ah[t2], bh, acc[t2][u]);
                    acc[t2][u] = MFMA16(ah[t2], bl, acc[t2][u]);
                    acc[t2][u] = MFMA16(al[t2], bh, acc[t2][u]);
                }
            }
        }
        __syncthreads();
    }

    // ---- cross-slice reduce + epilogue (C/D: row = q*4+reg, col = r)
    if (slice == 1) {
#pragma unroll
        for (int t2 = 0; t2 < 2; ++t2)
#pragma unroll
            for (int u = 0; u < 4; ++u)
#pragma unroll
                for (int reg = 0; reg < 4; ++reg)
                    Red[(rowq * 32 + t2 * 16 + q * 4 + reg) * 64 + u * 16 + r]
                        = acc[t2][u][reg];
    }
    __syncthreads();
    if (slice == 0) {
#pragma unroll
        for (int t2 = 0; t2 < 2; ++t2)
#pragma unroll
            for (int u = 0; u < 4; ++u) {
                int col = bn0 + u * 16 + r;
                float bw = bW[col];
#pragma unroll
                for (int reg = 0; reg < 4; ++reg) {
                    int ml = rowq * 32 + t2 * 16 + q * 4 + reg;
                    float v = acc[t2][u][reg]
                            + Red[ml * 64 + u * 16 + r];
                    float x = relu_f(v + bw);
                    _Float16 hi = (_Float16)x;
                    size_t o = (size_t)(bm0 + ml) * EMBED + col;
                    Cp[o] = hi;
                    Cp[o + hoff] = (_Float16)(x - (float)hi);
                }
            }
    }
}

// ---------------------------------------------------------------------------
// 32x32 split-K kernel (h=3,4; M multiple of 32). grid = (M/32, 16).
__global__ __launch_bounds__(256)
void gemm_splitk32(const _Float16* __restrict__ Ap, const _Float16* __restrict__ Wp,
                   const float* __restrict__ bW,
                   _Float16* __restrict__ Cp, int hoff)
{
    __shared__ float red[4096];

    int tid = threadIdx.x;
    int wave = tid >> 6, lane = tid & 63;
    int q = lane >> 4, r = lane & 15;
    int m0 = blockIdx.x * 32, n0 = blockIdx.y * 32;

    const _Float16 *pAh[2], *pAl[2];
#pragma unroll
    for (int mi = 0; mi < 2; ++mi) {
        int m = m0 + mi * 16 + r;
        int prow = 2 * m + (wave >> 1);          // child row in prev level
        int kb = (wave & 1) * 256;               // k-offset within child
        pAh[mi] = Ap + (size_t)prow * EMBED + kb + q * 8;
        pAl[mi] = pAh[mi] + hoff;
    }
    const _Float16* pB[2];
#pragma unroll
    for (int u = 0; u < 2; ++u)
        pB[u] = Wp + (size_t)(blockIdx.y * 2 + u) * 16384
              + (size_t)(wave * 8) * 512 + lane * 8;

    floatx4 acc[2][2];
#pragma unroll
    for (int mi = 0; mi < 2; ++mi)
#pragma unroll
        for (int u = 0; u < 2; ++u) acc[mi][u] = (floatx4){0.f, 0.f, 0.f, 0.f};

#pragma unroll
    for (int s = 0; s < 8; ++s) {
        half8 ah[2], al[2], bh[2], bl[2];
#pragma unroll
        for (int mi = 0; mi < 2; ++mi) {
            ah[mi] = *(const half8*)(pAh[mi] + s * 32);
            al[mi] = *(const half8*)(pAl[mi] + s * 32);
        }
#pragma unroll
        for (int u = 0; u < 2; ++u) {
            bh[u] = *(const half8*)(pB[u] + s * 512);
            bl[u] = *(const half8*)(pB[u] + s * 512 + WOFF);
        }
#pragma unroll
        for (int mi = 0; mi < 2; ++mi)
#pragma unroll
            for (int u = 0; u < 2; ++u) {
                acc[mi][u] = MFMA16(ah[mi], bh[u], acc[mi][u]);
                acc[mi][u] = MFMA16(ah[mi], bl[u], acc[mi][u]);
                acc[mi][u] = MFMA16(al[mi], bh[u], acc[mi][u]);
            }
    }

#pragma unroll
    for (int mi = 0; mi < 2; ++mi)
#pragma unroll
        for (int u = 0; u < 2; ++u)
#pragma unroll
            for (int reg = 0; reg < 4; ++reg)
                red[wave * 1024 + (mi * 16 + q * 4 + reg) * 32 + u * 16 + r]
                    = acc[mi][u][reg];
    __syncthreads();

    int row = tid >> 3, c4 = (tid & 7) * 4;
    _Float16 hi4[4], lo4[4];
#pragma unroll
    for (int j = 0; j < 4; ++j) {
        int c = row * 32 + c4 + j;
        float v = red[c] + red[1024 + c] + red[2048 + c] + red[3072 + c];
        float x = relu_f(v + bW[n0 + c4 + j]);
        _Float16 hi = (_Float16)x;
        hi4[j] = hi;
        lo4[j] = (_Float16)(x - (float)hi);
    }
    size_t o = (size_t)(m0 + row) * EMBED + n0 + c4;
#pragma unroll
    for (int j = 0; j < 4; ++j) { Cp[o + j] = hi4[j]; Cp[o + hoff + j] = lo4[j]; }
}

// ---------------------------------------------------------------------------
// 16x16 split-K kernel (h=5..13). grid = (ceil(M/16), 32).
__global__ __launch_bounds__(256)
void gemm_splitk(const _Float16* __restrict__ Ap, const _Float16* __restrict__ Wp,
                 const float* __restrict__ bW,
                 _Float16* __restrict__ Cp, int hoff, int M)
{
    __shared__ float red[1024];

    int tid = threadIdx.x;
    int wave = tid >> 6, lane = tid & 63;
    int q = lane >> 4, r = lane & 15;
    int mt = blockIdx.x, u = blockIdx.y;

    int m = mt * 16 + r;
    if (m >= M) m = M - 1;
    int prow = 2 * m + (wave >> 1);
    int kb = (wave & 1) * 256;
    const _Float16* pAh = Ap + (size_t)prow * EMBED + kb + q * 8;
    const _Float16* pAl = pAh + hoff;
    const _Float16* pB  = Wp + (size_t)u * 16384 + (size_t)(wave * 8) * 512 + lane * 8;

    floatx4 acc = (floatx4){0.f, 0.f, 0.f, 0.f};
#pragma unroll
    for (int s = 0; s < 8; ++s) {
        half8 ah = *(const half8*)(pAh + s * 32);
        half8 al = *(const half8*)(pAl + s * 32);
        half8 bh = *(const half8*)(pB + s * 512);
        half8 bl = *(const half8*)(pB + s * 512 + WOFF);
        acc = MFMA16(ah, bh, acc);
        acc = MFMA16(ah, bl, acc);
        acc = MFMA16(al, bh, acc);
    }
#pragma unroll
    for (int reg = 0; reg < 4; ++reg)
        red[wave * 256 + (q * 4 + reg) * 16 + r] = acc[reg];
    __syncthreads();

    int row = tid >> 4, col = tid & 15;
    float v = red[row * 16 + col] + red[256 + row * 16 + col]
            + red[512 + row * 16 + col] + red[768 + row * 16 + col];
    int mm = mt * 16 + row;
    if (mm < M) {
        int colg = u * 16 + col;
        float x = relu_f(v + bW[colg]);
        _Float16 hi = (_Float16)x;
        size_t o = (size_t)mm * EMBED + colg;
        Cp[o] = hi;
        Cp[o + hoff] = (_Float16)(x - (float)hi);
    }
}

// ---------------------------------------------------------------------------
// Projection: buffer row j (level-major) -> out[idx(h,m)]. Level decode:
// h = 13 - floor(log2(16383 - j)), m = j - (16384 - 2^(14-h)).
__global__ __launch_bounds__(256)
void out_kernel(const _Float16* __restrict__ Hh, const _Float16* __restrict__ Hl,
                const float* __restrict__ P, const float* __restrict__ bP,
                float* __restrict__ out, int nNodes)
{
    int t = blockIdx.x * 256 + threadIdx.x;
    int j = t >> 6, lane = t & 63;
    if (j >= nNodes) return;
    int v = nNodes - j;                         // 16383 - j >= 1
    int h = 13 - (31 - __clz(v));
    int m = j - ((nNodes + 1) - (1 << (13 - h + 1)));
    int node = ((m + 1) << (h + 1)) - 2 - __popc(m);

    half8 hv = *(const half8*)(Hh + (size_t)j * EMBED + lane * 8);
    half8 lv = *(const half8*)(Hl + (size_t)j * EMBED + lane * 8);
    float hx[8];
#pragma unroll
    for (int k = 0; k < 8; ++k) hx[k] = (float)hv[k] + (float)lv[k];
    float s[5];
#pragma unroll
    for (int c = 0; c < 5; ++c) {
        const float* p = P + c * EMBED + lane * 8;
        float4 p0 = *(const float4*)p;
        float4 p1 = *(const float4*)(p + 4);
        s[c] = hx[0] * p0.x + hx[1] * p0.y + hx[2] * p0.z + hx[3] * p0.w
             + hx[4] * p1.x + hx[5] * p1.y + hx[6] * p1.z + hx[7] * p1.w;
    }
#pragma unroll
    for (int o = 32; o > 0; o >>= 1)
#pragma unroll
        for (int c = 0; c < 5; ++c)
            s[c] += __shfl_down(s[c], o, 64);
    if (lane == 0) {
#pragma unroll
        for (int c = 0; c < 5; ++c)
            out[(size_t)node * 5 + c] = s[c] + bP[c];
    }
}

// ---------------------------------------------------------------------------
extern "C" void kernel_launch(void* const* d_in, const int* in_sizes, int n_in,
                              void* d_out, int out_size, void* d_ws, size_t ws_size,
                              hipStream_t stream)
{
    const int*   word = (const int*)d_in[1];
    const float* emb  = (const float*)d_in[4];
    const float* W    = (const float*)d_in[5];
    const float* bW   = (const float*)d_in[6];
    const float* P    = (const float*)d_in[7];
    const float* bP   = (const float*)d_in[8];
    float* out = (float*)d_out;

    int nNodes  = in_sizes[0];            // 16383
    int nLeaves = (nNodes + 1) / 2;       // 8192
    int nRows   = nNodes + 1;             // 16384

    int hoff = nRows * EMBED;             // halves between Hh and Hl
    _Float16* Hh  = (_Float16*)d_ws;
    _Float16* Hl  = Hh + hoff;
    _Float16* Whp = Hl + hoff;            // hi; lo at +WOFF

    // level row offsets: roff(h) = 16384 - 2^(14-h)
    auto roff = [&](int h) { return nRows - (1 << (14 - h)); };

    packleaf<<<dim3(256), dim3(256), 0, stream>>>(
        W, emb, word, Whp, Hh, Hl, nLeaves);

    // h=1: M=4096, 128x64 tiles -> grid (32,8) = 256 blocks
    gemm_lvl2<<<dim3(32, 8), dim3(512), 0, stream>>>(
        Hh + (size_t)roff(0) * EMBED, Whp, bW,
        Hh + (size_t)roff(1) * EMBED, hoff);
    // h=2: M=2048, 128x64 tiles -> grid (16,8) = 128 blocks
    gemm_lvl2<<<dim3(16, 8), dim3(512), 0, stream>>>(
        Hh + (size_t)roff(1) * EMBED, Whp, bW,
        Hh + (size_t)roff(2) * EMBED, hoff);

    for (int h = 3; h <= 4; ++h) {        // M = 1024, 512
        int M = 1 << (13 - h);
        gemm_splitk32<<<dim3(M / 32, 16), dim3(256), 0, stream>>>(
            Hh + (size_t)roff(h - 1) * EMBED, Whp, bW,
            Hh + (size_t)roff(h) * EMBED, hoff);
    }
    for (int h = 5; h <= 13; ++h) {       // M = 256..1
        int M = 1 << (13 - h);
        gemm_splitk<<<dim3((M + 15) / 16, 32), dim3(256), 0, stream>>>(
            Hh + (size_t)roff(h - 1) * EMBED, Whp, bW,
            Hh + (size_t)roff(h) * EMBED, hoff, M);
    }
    out_kernel<<<dim3((nNodes * 64 + 255) / 256), dim3(256), 0, stream>>>(
        Hh, Hl, P, bP, out, nNodes);
}